// Round 7
// baseline (41.164 us; speedup 1.0000x reference)
//
#include <hip/hip_runtime.h>

// B=2048, T=8192, fp32 in, scalar fp32 out.
// d_in[0]=target_angle [B,T], d_in[1]=target_class [B,3],
// d_in[2]=pred_angle [B,T], d_in[3]=pred_class [B,3]
//
// Persistent software-pipelined streaming: 1024 blocks, each thread owns
// 8 contiguous floats in each of 8 grid-sweep chunks. 4-slot register ring:
// prologue issues chunks 0-3 (16 KB/wave nt loads in flight), steady state
// computes chunk c then issues c+4 into the freed slot -> memory stays
// continuously in flight; one reduce tail per 64 KB.

#define NTHREADS 256
#define ITERS 8
#define DEPTH 4

typedef float f32x4 __attribute__((ext_vector_type(4)));

__global__ __launch_bounds__(NTHREADS) void wma_partial_kernel(
    const float* __restrict__ ta, const float* __restrict__ pa,
    float* __restrict__ partial, int T)
{
    const int t = threadIdx.x;
    const int lane = t & 63;
    const long span = (long)gridDim.x * NTHREADS * 8;   // elements per sweep
    const long base = ((long)blockIdx.x * NTHREADS + t) * 8;
    const int col = (int)(base % T);  // span % T == 0 -> same col every chunk
    const bool edge0  = (lane == 0)  && (col > 0);       // col>0 -> col>=2
    const bool edge63 = (lane == 63) && (col + 8 < T);   // -> col+9 < T too

    f32x4 A[DEPTH][2], P[DEPTH][2];
    float em1[DEPTH], em2[DEPTH], ep8[DEPTH], ep9[DEPTH];

#define ISSUE(c) do {                                                     \
        const int s_ = (c) & (DEPTH - 1);                                 \
        const long e_ = base + (long)(c) * span;                          \
        const f32x4* tap_ = (const f32x4*)(ta + e_);                      \
        const f32x4* pap_ = (const f32x4*)(pa + e_);                      \
        A[s_][0] = __builtin_nontemporal_load(tap_);                      \
        A[s_][1] = __builtin_nontemporal_load(tap_ + 1);                  \
        P[s_][0] = __builtin_nontemporal_load(pap_);                      \
        P[s_][1] = __builtin_nontemporal_load(pap_ + 1);                  \
        em1[s_] = edge0  ? ta[e_ - 1] - pa[e_ - 1] : 0.0f;                \
        em2[s_] = edge0  ? ta[e_ - 2] - pa[e_ - 2] : 0.0f;                \
        ep8[s_] = edge63 ? ta[e_ + 8] - pa[e_ + 8] : 0.0f;                \
        ep9[s_] = edge63 ? ta[e_ + 9] - pa[e_ + 9] : 0.0f;                \
    } while (0)

    // ---- prologue: fill the ring (16 KB/wave in flight) ----
    ISSUE(0); ISSUE(1); ISSUE(2); ISSUE(3);

    float acc = 0.0f;
#pragma unroll
    for (int c = 0; c < ITERS; ++c) {
        const int s = c & (DEPTH - 1);
        const float d0 = A[s][0].x - P[s][0].x;
        const float d1 = A[s][0].y - P[s][0].y;
        const float d2 = A[s][0].z - P[s][0].z;
        const float d3 = A[s][0].w - P[s][0].w;
        const float d4 = A[s][1].x - P[s][1].x;
        const float d5 = A[s][1].y - P[s][1].y;
        const float d6 = A[s][1].z - P[s][1].z;
        const float d7 = A[s][1].w - P[s][1].w;

        float dm2 = __shfl_up(d6, 1, 64);
        float dm1 = __shfl_up(d7, 1, 64);
        float dp8 = __shfl_down(d0, 1, 64);
        float dp9 = __shfl_down(d1, 1, 64);
        if (lane == 0)  { dm2 = em2[s]; dm1 = em1[s]; }
        if (lane == 63) { dp8 = ep8[s]; dp9 = ep9[s]; }

        float w;
        w = 0.05f*dm2 + 0.1f*dm1 + 0.7f*d0 + 0.1f*d1  + 0.05f*d2;  acc += w*w;
        w = 0.05f*dm1 + 0.1f*d0  + 0.7f*d1 + 0.1f*d2  + 0.05f*d3;  acc += w*w;
        w = 0.05f*d0  + 0.1f*d1  + 0.7f*d2 + 0.1f*d3  + 0.05f*d4;  acc += w*w;
        w = 0.05f*d1  + 0.1f*d2  + 0.7f*d3 + 0.1f*d4  + 0.05f*d5;  acc += w*w;
        w = 0.05f*d2  + 0.1f*d3  + 0.7f*d4 + 0.1f*d5  + 0.05f*d6;  acc += w*w;
        w = 0.05f*d3  + 0.1f*d4  + 0.7f*d5 + 0.1f*d6  + 0.05f*d7;  acc += w*w;
        w = 0.05f*d4  + 0.1f*d5  + 0.7f*d6 + 0.1f*d7  + 0.05f*dp8; acc += w*w;
        w = 0.05f*d5  + 0.1f*d6  + 0.7f*d7 + 0.1f*dp8 + 0.05f*dp9; acc += w*w;

        // refill the slot just consumed (keeps the pipe full)
        if (c + DEPTH < ITERS) ISSUE(c + DEPTH);
    }
#undef ISSUE

    // ---- one wave reduce per 64 KB, then cross-wave via tiny LDS ----
#pragma unroll
    for (int off = 32; off; off >>= 1) acc += __shfl_down(acc, off, 64);

    __shared__ float wsum[NTHREADS / 64];
    if ((t & 63) == 0) wsum[t >> 6] = acc;
    __syncthreads();
    if (t == 0) {
        float b = 0.0f;
#pragma unroll
        for (int i = 0; i < NTHREADS / 64; ++i) b += wsum[i];
        partial[blockIdx.x] = b;
    }
}

#define FIN_THREADS 1024

__global__ __launch_bounds__(FIN_THREADS) void finalize_kernel(
    const float* __restrict__ partial, int nPartial,
    const float* __restrict__ tc, const float* __restrict__ pc, int nClass,
    float* __restrict__ out)
{
    const int t = threadIdx.x;

    float sa = 0.0f;
    for (int i = t; i < nPartial; i += FIN_THREADS) sa += partial[i];

    float sc = 0.0f;
    for (int i = t; i < nClass; i += FIN_THREADS) {
        const float d = tc[i] - pc[i];
        sc += d * d;
    }

#pragma unroll
    for (int off = 32; off; off >>= 1) {
        sa += __shfl_down(sa, off, 64);
        sc += __shfl_down(sc, off, 64);
    }

    __shared__ float ra[FIN_THREADS / 64], rc[FIN_THREADS / 64];
    if ((t & 63) == 0) { ra[t >> 6] = sa; rc[t >> 6] = sc; }
    __syncthreads();
    if (t == 0) {
        float a = 0.0f, c = 0.0f;
#pragma unroll
        for (int i = 0; i < FIN_THREADS / 64; ++i) { a += ra[i]; c += rc[i]; }
        out[0] = 0.8f * a + 0.2f * c;
    }
}

extern "C" void kernel_launch(void* const* d_in, const int* in_sizes, int n_in,
                              void* d_out, int out_size, void* d_ws, size_t ws_size,
                              hipStream_t stream)
{
    const float* ta = (const float*)d_in[0];  // target_angle [B,T]
    const float* tc = (const float*)d_in[1];  // target_class [B,3]
    const float* pa = (const float*)d_in[2];  // pred_angle  [B,T]
    const float* pc = (const float*)d_in[3];  // pred_class  [B,3]
    float* out = (float*)d_out;

    const int nAngle = in_sizes[0];           // B*T
    const int nClass = in_sizes[1];           // B*3
    const int T = 8192;
    const int grid = nAngle / (NTHREADS * 8 * ITERS);   // 1024

    float* partial = (float*)d_ws;            // grid floats (4 KB) < ws_size

    wma_partial_kernel<<<grid, NTHREADS, 0, stream>>>(ta, pa, partial, T);
    finalize_kernel<<<1, FIN_THREADS, 0, stream>>>(partial, grid, tc, pc, nClass, out);
}